// Round 17
// baseline (585.050 us; speedup 1.0000x reference)
//
#include <hip/hip_runtime.h>
#include <stdint.h>

// GRU decoder: 65536 rows, H=256, T=12, D_OUT=64.
// R17 = R16 (register-state, swapped-operand MFMA, 8 waves x 32 rows,
// 256 blocks = 1/CU, ring-3 lane-linear panel stream, conflict-free,
// builtin permlane repack + rcpf) + DEFERRED PACKS: the sigmoid/tanh pack
// of phase P executes inside phase P+1's body, overlapping P+1's
// ds_read/MFMA latency. Only W2_3's pack is inline (proj needs hn next
// phase). Acc rotation {A,B} + o-pair; B and o disjoint -> peak acc 64
// regs, same as R16 (no spill). Arithmetic identical, reordered only.

#define TSTEPS 12
#define AS3 __attribute__((address_space(3)))

typedef _Float16 f16x8 __attribute__((ext_vector_type(8)));
typedef _Float16 f16x2 __attribute__((ext_vector_type(2)));
typedef float    f32x16 __attribute__((ext_vector_type(16)));
typedef float    f32x4  __attribute__((ext_vector_type(4)));
typedef uint32_t u32x4  __attribute__((ext_vector_type(4)));
typedef uint32_t u32x2  __attribute__((ext_vector_type(2)));

typedef AS3 uint8_t       u8l;
typedef const AS3 uint8_t cu8l;

// ws: f16 weights (panels of 64 rows x 256 k = 32KB, row-major):
//   0-3 gate-r(folded), 4-7 gate-z(folded), 8-11 W1, 12-15 W2, 16 Wp
// then f32 bias block in C-layout e-pattern order.
#define WG_E (512*256)
#define W1_E (256*256)
#define WS_W_F16 (WG_E + 2*W1_E + 64*256)
#define BIAS_F32 832
#define WS_BYTES (WS_W_F16*2 + BIAS_F32*4)

__global__ void prep_weights(const float* __restrict__ gw,
                             const float* __restrict__ ow,
                             const float* __restrict__ pw,
                             const float* __restrict__ gb,
                             const float* __restrict__ ob,
                             const float* __restrict__ pb,
                             _Float16* __restrict__ ws)
{
    int idx = blockIdx.x*256 + threadIdx.x;
    if (idx < WG_E) {                           // folded gates
        int j = idx >> 8, k = idx & 255;
        ws[idx] = (_Float16)(gw[j*512 + k] + gw[j*512 + 256 + k]);
    } else if (idx < WG_E + W1_E) {             // W1 = out_w[:, :256]
        int i = idx - WG_E; int r = i >> 8, c = i & 255;
        ws[idx] = (_Float16)ow[r*512 + c];
    } else if (idx < WG_E + 2*W1_E) {           // W2 = out_w[:, 256:]
        int i = idx - WG_E - W1_E; int r = i >> 8, c = i & 255;
        ws[idx] = (_Float16)ow[r*512 + 256 + c];
    } else if (idx < WS_W_F16) {                // Wp
        ws[idx] = (_Float16)pw[idx - WG_E - 2*W1_E];
    } else if (idx < WS_W_F16 + BIAS_F32) {     // expanded biases (f32)
        int b = idx - WS_W_F16;
        float* bd = (float*)(ws + WS_W_F16);
        if (b < 768) {
            int type = b >> 8, r = b & 255;
            int c = r >> 6, n = (r >> 5) & 1, kg = (r >> 4) & 1, e = r & 15;
            int col = 64*c + 32*n + 4*kg + (e & 3) + 8*(e >> 2);
            bd[b] = (type == 0) ? gb[col] : (type == 1) ? gb[256 + col] : ob[col];
        } else {
            int i = b - 768;
            int n = (i >> 5) & 1, kg = (i >> 4) & 1, e = i & 15;
            bd[b] = pb[32*n + 4*kg + (e & 3) + 8*(e >> 2)];
        }
    }
}

__device__ __forceinline__ float sigm(float x) {
    return __builtin_amdgcn_rcpf(1.0f + __expf(-x));
}
__device__ __forceinline__ float tanh_(float x) {
    return 1.0f - 2.0f*__builtin_amdgcn_rcpf(1.0f + __expf(2.0f*x));
}

// stage one 32KB panel (8 waves x 4 gll16) into lane-linear chunk layout:
// dest chunk c = w*4 + i holds (ks=c>>1, tile=c&1); lane l supplies
// W[tile*32 + (l&31)][ks*16 + (l>>5)*8 ..+7] from the row-major panel.
__device__ __forceinline__ void stage(const uint8_t* __restrict__ Wp,
                                      u8l* slot, int w, int laneC)
{
    #pragma unroll
    for (int i = 0; i < 4; ++i) {
        int c    = w*4 + i;                   // chunk 0..31 (wave-uniform)
        int ks   = c >> 1, tile = c & 1;
        int s    = laneC + tile*16384 + ks*32;  // per-lane global source
        __builtin_amdgcn_global_load_lds(
            (const __attribute__((address_space(1))) uint32_t*)(Wp + s),
            (AS3 uint32_t*)(slot + w*4096 + i*1024), 16, 0, 0);
    }
}

// load f32x16 bias (broadcast within kg-half)
__device__ __forceinline__ f32x16 ldbias(cu8l* p) {
    f32x16 r;
    #pragma unroll
    for (int j = 0; j < 4; ++j) {
        f32x4 t = *(const AS3 f32x4*)(p + j*16);
        r[j*4+0]=t[0]; r[j*4+1]=t[1]; r[j*4+2]=t[2]; r[j*4+3]=t[3];
    }
    return r;
}

// C-layout e-pattern (8 outcols) -> B-frag f16x8 via permlane32_swap builtin
// (compiler inserts the VALU->permlane hazard waits; raw asm did not - R14/15).
__device__ __forceinline__ f16x8 pk8(uint32_t w01, uint32_t w23,
                                     uint32_t w45, uint32_t w67) {
    u32x2 p0 = __builtin_amdgcn_permlane32_swap(w01, w45, false, false);
    u32x2 p1 = __builtin_amdgcn_permlane32_swap(w23, w67, false, false);
    u32x4 u = { p0[0], p1[0], p0[1], p1[1] };
    return __builtin_bit_cast(f16x8, u);
}
__device__ __forceinline__ f16x8 pkS(const f32x16& a, int off) {
    f16x2 a01 = {(_Float16)sigm(a[off+0]), (_Float16)sigm(a[off+1])};
    f16x2 a23 = {(_Float16)sigm(a[off+2]), (_Float16)sigm(a[off+3])};
    f16x2 a45 = {(_Float16)sigm(a[off+4]), (_Float16)sigm(a[off+5])};
    f16x2 a67 = {(_Float16)sigm(a[off+6]), (_Float16)sigm(a[off+7])};
    return pk8(__builtin_bit_cast(uint32_t, a01), __builtin_bit_cast(uint32_t, a23),
               __builtin_bit_cast(uint32_t, a45), __builtin_bit_cast(uint32_t, a67));
}
__device__ __forceinline__ f16x8 pkT(const f32x16& a, int off) {
    f16x2 a01 = {(_Float16)tanh_(a[off+0]), (_Float16)tanh_(a[off+1])};
    f16x2 a23 = {(_Float16)tanh_(a[off+2]), (_Float16)tanh_(a[off+3])};
    f16x2 a45 = {(_Float16)tanh_(a[off+4]), (_Float16)tanh_(a[off+5])};
    f16x2 a67 = {(_Float16)tanh_(a[off+6]), (_Float16)tanh_(a[off+7])};
    return pk8(__builtin_bit_cast(uint32_t, a01), __builtin_bit_cast(uint32_t, a23),
               __builtin_bit_cast(uint32_t, a45), __builtin_bit_cast(uint32_t, a67));
}

// one panel GEMM: acc_n += W[32n+(l&31), k] * B. Reads are lane-linear
// contiguous 1KB per instruction: base + lane*16 + imm (2ks+tile)*1024.
__device__ __forceinline__ void gemm2(cu8l* panL, const f16x8* B,
                                      f32x16& a0, f32x16& a1) {
    #pragma unroll
    for (int ks = 0; ks < 16; ++ks) {
        f16x8 w0 = *(const AS3 f16x8*)(panL + ks*2048);
        f16x8 w1 = *(const AS3 f16x8*)(panL + ks*2048 + 1024);
        a0 = __builtin_amdgcn_mfma_f32_32x32x16_f16(w0, B[ks], a0, 0, 0, 0);
        a1 = __builtin_amdgcn_mfma_f32_32x32x16_f16(w1, B[ks], a1, 0, 0, 0);
    }
}

// phase: wait panel (per-wave vmcnt(4): 2 stages of 4 in flight) -> barrier
// -> stage 2-ahead -> body (current GEMM + previous phase's deferred pack)
#define PHASE(SP, ...) do {                                                 \
    asm volatile("s_waitcnt vmcnt(4)" ::: "memory");                        \
    asm volatile("s_waitcnt lgkmcnt(0)" ::: "memory");                      \
    __builtin_amdgcn_s_barrier();                                           \
    asm volatile("" ::: "memory");                                          \
    stage(W + (SP)*32768, WbL + sS*32768, w, laneC);                        \
    { cu8l* panL = WbL + sC*32768 + LB; (void)panL; __VA_ARGS__; }          \
    sC = (sC == 2) ? 0 : sC + 1;                                            \
    sS = (sS == 2) ? 0 : sS + 1;                                            \
} while (0)

// ---- phase building blocks (multi-statement, comma-free at top level) ----
#define GEMM_R(C, X0, X1)                                                   \
    X0 = ldbias(bK + (C)*256);                                              \
    X1 = ldbias(bK + (C)*256 + 128);                                        \
    gemm2(panL, h, X0, X1);
#define PACK_R(C, X0, X1)                                                   \
    rh[4*(C)+0] = pkS(X0, 0)*h[4*(C)+0];                                    \
    rh[4*(C)+1] = pkS(X0, 8)*h[4*(C)+1];                                    \
    rh[4*(C)+2] = pkS(X1, 0)*h[4*(C)+2];                                    \
    rh[4*(C)+3] = pkS(X1, 8)*h[4*(C)+3];
#define GEMM_Z(C, X0, X1)                                                   \
    X0 = ldbias(bK + 1024 + (C)*256);                                       \
    X1 = ldbias(bK + 1024 + (C)*256 + 128);                                 \
    gemm2(panL, h, X0, X1);
#define PACK_Z(X0, X1)                                                      \
    zb[0] = pkS(X0, 0); zb[1] = pkS(X0, 8);                                 \
    zb[2] = pkS(X1, 0); zb[3] = pkS(X1, 8);
#define GEMM_W1(C)                                                          \
    o0 = ldbias(bK + 2048 + (C)*256);                                       \
    o1 = ldbias(bK + 2048 + (C)*256 + 128);                                 \
    gemm2(panL, h, o0, o1);
#define GEMM_W2() gemm2(panL, rh, o0, o1);
#define PACK_W2(C) {                                                        \
    f16x8 u0 = pkT(o0, 0);                                                  \
    f16x8 u1 = pkT(o0, 8);                                                  \
    f16x8 u2 = pkT(o1, 0);                                                  \
    f16x8 u3 = pkT(o1, 8);                                                  \
    hn[4*(C)+0] = u0 + zb[0]*(h[4*(C)+0] - u0);                             \
    hn[4*(C)+1] = u1 + zb[1]*(h[4*(C)+1] - u1);                             \
    hn[4*(C)+2] = u2 + zb[2]*(h[4*(C)+2] - u2);                             \
    hn[4*(C)+3] = u3 + zb[3]*(h[4*(C)+3] - u3); }

__global__ __launch_bounds__(512, 1)
void gru_dec(const float* __restrict__ h_in, const _Float16* __restrict__ Wf,
             float* __restrict__ out)
{
    __shared__ __align__(16) uint8_t lds_[101632];
    u8l* ldsb = (u8l*)lds_;
    u8l* WbL  = ldsb;                     // 3 x 32KB panel ring
    u8l* biasL = ldsb + 98304;            // 3.3KB expanded biases
    const uint8_t* W = (const uint8_t*)Wf;

    const int tid  = threadIdx.x;
    const int lane = tid & 63;
    const int w    = tid >> 6;            // wave 0..7, owns 32 rows
    const int bl31 = lane & 31;
    const int kg   = lane >> 5;
    const size_t rowg = (size_t)blockIdx.x*256 + w*32 + bl31;

    const int laneC = bl31*512 + kg*16;   // per-lane stage source constant
    const int LB    = lane*16;            // per-lane ds-read base

    // ---- h -> registers as B-frags: h[ks] = h[rowg, 16ks+8kg+0..7] ----
    f16x8 h[16], rh[16], hn[16];
    {
        const float* hs = h_in + rowg*256 + kg*8;
        #pragma unroll
        for (int ks = 0; ks < 16; ++ks) {
            f32x4 x = *(const f32x4*)(hs + ks*16);
            f32x4 y = *(const f32x4*)(hs + ks*16 + 4);
            f16x8 v = {(_Float16)x[0],(_Float16)x[1],(_Float16)x[2],(_Float16)x[3],
                       (_Float16)y[0],(_Float16)y[1],(_Float16)y[2],(_Float16)y[3]};
            h[ks] = v;
        }
    }
    // ---- biases ws -> LDS ----
    {
        const float* bsrc = (const float*)(Wf + WS_W_F16);
        for (int i = tid; i < BIAS_F32; i += 512)
            *(AS3 float*)(biasL + i*4) = bsrc[i];
    }
    __syncthreads();                      // drains h loads + bias writes

    cu8l* bK = biasL + kg*64;

    stage(W + 0*32768, WbL,         w, laneC);   // prologue: panel r0
    stage(W + 1*32768, WbL + 32768, w, laneC);   // panel r1
    int sC = 0, sS = 2;

    for (int t = 0; t < TSTEPS; ++t) {
        f32x16 A0, A1, B0, B1, o0, o1;
        f16x8 zb[4];

        // compute order (panels): 0,1,2,3 | 4,8,12 | 5,9,13 | 6,10,14 |
        //                         7,11,15 | 16.  Stage arg = 2 ahead.
        PHASE(2,  { GEMM_R(0, A0, A1) });
        PHASE(3,  { GEMM_R(1, B0, B1)  PACK_R(0, A0, A1) });
        PHASE(4,  { GEMM_R(2, A0, A1)  PACK_R(1, B0, B1) });
        PHASE(8,  { GEMM_R(3, B0, B1)  PACK_R(2, A0, A1) });
        PHASE(12, { GEMM_Z(0, A0, A1)  PACK_R(3, B0, B1) });
        PHASE(5,  { GEMM_W1(0)         PACK_Z(A0, A1) });
        PHASE(9,  { GEMM_W2() });
        PHASE(13, { GEMM_Z(1, A0, A1)  PACK_W2(0) });
        PHASE(6,  { GEMM_W1(1)         PACK_Z(A0, A1) });
        PHASE(10, { GEMM_W2() });
        PHASE(14, { GEMM_Z(2, A0, A1)  PACK_W2(1) });
        PHASE(7,  { GEMM_W1(2)         PACK_Z(A0, A1) });
        PHASE(11, { GEMM_W2() });
        PHASE(15, { GEMM_Z(3, A0, A1)  PACK_W2(2) });
        PHASE(16, { GEMM_W1(3)         PACK_Z(A0, A1) });
        PHASE(0,  { GEMM_W2()          PACK_W2(3) });   // hn complete

        // ---- proj (panel 16): out_t = hn @ Wp^T + pb; h <- hn ----
        PHASE(1, {
            A0 = ldbias(bK + 3072);
            A1 = ldbias(bK + 3072 + 128);
            gemm2(panL, hn, A0, A1);
            float* op = out + (rowg*TSTEPS + t)*64 + 4*kg;
            _Pragma("unroll")
            for (int j = 0; j < 4; ++j) {
                f32x4 v0 = {A0[4*j], A0[4*j+1], A0[4*j+2], A0[4*j+3]};
                f32x4 v1 = {A1[4*j], A1[4*j+1], A1[4*j+2], A1[4*j+3]};
                *(f32x4*)(op + 8*j)      = v0;
                *(f32x4*)(op + 32 + 8*j) = v1;
            }
            _Pragma("unroll")
            for (int i = 0; i < 16; ++i) h[i] = hn[i];
        });
    }
}

extern "C" void kernel_launch(void* const* d_in, const int* in_sizes, int n_in,
                              void* d_out, int out_size, void* d_ws, size_t ws_size,
                              hipStream_t stream) {
    // inputs: 0:x(=12) 1:h 2:gate_w 3:gate_b 4:out_w 5:out_b 6:proj_w 7:proj_b
    const float* h  = (const float*)d_in[1];
    const float* gw = (const float*)d_in[2];
    const float* gb = (const float*)d_in[3];
    const float* ow = (const float*)d_in[4];
    const float* ob = (const float*)d_in[5];
    const float* pw = (const float*)d_in[6];
    const float* pb = (const float*)d_in[7];
    if (ws_size < (size_t)WS_BYTES) return;
    _Float16* ws = (_Float16*)d_ws;

    hipLaunchKernelGGL(prep_weights, dim3((WS_W_F16 + BIAS_F32 + 255)/256), dim3(256),
                       0, stream, gw, ow, pw, gb, ob, pb, ws);
    hipLaunchKernelGGL(gru_dec, dim3(65536/256), dim3(512), 0, stream,
                       h, ws, (float*)d_out);
}